// Round 1
// baseline (529.222 us; speedup 1.0000x reference)
//
#include <hip/hip_runtime.h>
#include <hip/hip_bf16.h>
#include <stdint.h>

#define N_ 4096
#define H_ 1024
#define V_ 16384

using bf16x8 = __attribute__((ext_vector_type(8))) short;
using f32x4  = __attribute__((ext_vector_type(4))) float;

__device__ inline ushort f2bf(float f) {
    // round-to-nearest-even bf16 (data has no NaN/inf)
    union { float f; uint32_t u; } v; v.f = f;
    uint32_t u = v.u;
    uint32_t lsb = (u >> 16) & 1u;
    u += 0x7fffu + lsb;
    return (ushort)(u >> 16);
}

// 8 floats -> 8 bf16 per thread
__global__ void cast_f32_to_bf16(const float* __restrict__ in, ushort* __restrict__ out) {
    size_t i = ((size_t)blockIdx.x * blockDim.x + threadIdx.x) * 8;
    float4 a = *(const float4*)(in + i);
    float4 b = *(const float4*)(in + i + 4);
    union { ushort h[8]; uint4 u; } p;
    p.h[0] = f2bf(a.x); p.h[1] = f2bf(a.y); p.h[2] = f2bf(a.z); p.h[3] = f2bf(a.w);
    p.h[4] = f2bf(b.x); p.h[5] = f2bf(b.y); p.h[6] = f2bf(b.z); p.h[7] = f2bf(b.w);
    *(uint4*)(out + i) = p.u;
}

#define BM 128
#define BN 128
#define BK 32

// C[m,v] = sum_k A[m,k]*W[v,k]; fused: sum((C + bias[v] - target[m,v])^2) per block
__global__ __launch_bounds__(256, 2) void gemm_mse(
    const ushort* __restrict__ Abf,   // N x H (bf16 bits)
    const ushort* __restrict__ Wbf,   // V x H (bf16 bits)
    const float*  __restrict__ target,// N x V
    const float*  __restrict__ bias,  // V
    float* __restrict__ partials)     // one per block
{
    __shared__ ushort As[BM * BK];
    __shared__ ushort Bs[BN * BK];
    __shared__ float red[4];

    const int tid  = threadIdx.x;
    const int w    = tid >> 6;        // wave 0..3
    const int lane = tid & 63;
    const int quad = lane >> 4;
    const int l16  = lane & 15;
    const int wm   = w >> 1;          // 2x2 wave grid, 64x64 each
    const int wn   = w & 1;

    const int rowBase = blockIdx.y * BM;  // N dim
    const int colBase = blockIdx.x * BN;  // V dim

    f32x4 acc[4][4];
#pragma unroll
    for (int i = 0; i < 4; ++i)
#pragma unroll
        for (int j = 0; j < 4; ++j) acc[i][j] = (f32x4){0.f, 0.f, 0.f, 0.f};

    // staging: each global_load_lds covers 1024B = 16 rows x 32 bf16
    const int ldrow = lane >> 2;          // 0..15
    const int ldk   = (lane & 3) * 8;     // 0,8,16,24 (elements)

    for (int k0 = 0; k0 < H_; k0 += BK) {
        __syncthreads();
#pragma unroll
        for (int c = 0; c < 2; ++c) {
            const int chunk = w * 2 + c;  // 0..7, wave-uniform
            const ushort* ga = Abf + (size_t)(rowBase + chunk * 16 + ldrow) * H_ + k0 + ldk;
            __builtin_amdgcn_global_load_lds(
                (const __attribute__((address_space(1))) void*)ga,
                (__attribute__((address_space(3))) void*)(As + chunk * 512), 16, 0, 0);
            const ushort* gb = Wbf + (size_t)(colBase + chunk * 16 + ldrow) * H_ + k0 + ldk;
            __builtin_amdgcn_global_load_lds(
                (const __attribute__((address_space(1))) void*)gb,
                (__attribute__((address_space(3))) void*)(Bs + chunk * 512), 16, 0, 0);
        }
        __syncthreads();

        bf16x8 af[4], bfr[4];
#pragma unroll
        for (int i = 0; i < 4; ++i)
            af[i] = *(const bf16x8*)(As + (wm * 64 + i * 16 + l16) * BK + quad * 8);
#pragma unroll
        for (int j = 0; j < 4; ++j)
            bfr[j] = *(const bf16x8*)(Bs + (wn * 64 + j * 16 + l16) * BK + quad * 8);
#pragma unroll
        for (int i = 0; i < 4; ++i)
#pragma unroll
            for (int j = 0; j < 4; ++j)
                acc[i][j] = __builtin_amdgcn_mfma_f32_16x16x32_bf16(af[i], bfr[j], acc[i][j], 0, 0, 0);
    }

    // epilogue: D element at m = quad*4 + reg, n = l16 (per-16x16 frag)
    float sum = 0.f;
    float biasj[4];
#pragma unroll
    for (int j = 0; j < 4; ++j) biasj[j] = bias[colBase + wn * 64 + j * 16 + l16];

#pragma unroll
    for (int i = 0; i < 4; ++i) {
#pragma unroll
        for (int r = 0; r < 4; ++r) {
            const int gm = rowBase + wm * 64 + i * 16 + quad * 4 + r;
            const float* trow = target + (size_t)gm * V_ + colBase + wn * 64 + l16;
#pragma unroll
            for (int j = 0; j < 4; ++j) {
                float d = acc[i][j][r] + biasj[j] - trow[j * 16];
                sum += d * d;
            }
        }
    }

    // block reduction
#pragma unroll
    for (int off = 32; off; off >>= 1) sum += __shfl_down(sum, off, 64);
    if (lane == 0) red[w] = sum;
    __syncthreads();
    if (tid == 0)
        partials[blockIdx.y * gridDim.x + blockIdx.x] = red[0] + red[1] + red[2] + red[3];
}

__global__ void finalize_kernel(const float* __restrict__ partials, float* __restrict__ out, int n) {
    float s = 0.f;
    for (int i = threadIdx.x; i < n; i += 256) s += partials[i];
#pragma unroll
    for (int off = 32; off; off >>= 1) s += __shfl_down(s, off, 64);
    __shared__ float red[4];
    const int w = threadIdx.x >> 6, lane = threadIdx.x & 63;
    if (lane == 0) red[w] = s;
    __syncthreads();
    if (threadIdx.x == 0)
        out[0] = (red[0] + red[1] + red[2] + red[3]) * (1.0f / ((float)N_ * (float)V_));
}

extern "C" void kernel_launch(void* const* d_in, const int* in_sizes, int n_in,
                              void* d_out, int out_size, void* d_ws, size_t ws_size,
                              hipStream_t stream) {
    const float* input  = (const float*)d_in[0];  // N x H
    const float* weight = (const float*)d_in[1];  // V x H
    const float* target = (const float*)d_in[2];  // N x V
    const float* bias   = (const float*)d_in[3];  // V
    float* out = (float*)d_out;

    ushort* Abf = (ushort*)d_ws;                      // N*H bf16
    ushort* Wbf = Abf + (size_t)N_ * H_;              // V*H bf16
    float* partials = (float*)(Wbf + (size_t)V_ * H_);// (N/128)*(V/128) floats

    cast_f32_to_bf16<<<(N_ * H_) / (256 * 8), 256, 0, stream>>>(input, Abf);
    cast_f32_to_bf16<<<(V_ * H_) / (256 * 8), 256, 0, stream>>>(weight, Wbf);

    dim3 grid(V_ / BN, N_ / BM);  // 128 x 32 = 4096 blocks
    gemm_mse<<<grid, 256, 0, stream>>>(Abf, Wbf, target, bias, partials);

    finalize_kernel<<<1, 256, 0, stream>>>(partials, out, (V_ / BN) * (N_ / BM));
}